// Round 3
// baseline (118.904 us; speedup 1.0000x reference)
//
#include <hip/hip_runtime.h>

typedef __bf16 v8bf __attribute__((ext_vector_type(8)));
typedef float v4f __attribute__((ext_vector_type(4)));
typedef unsigned short u16x8 __attribute__((ext_vector_type(8)));

__device__ __forceinline__ unsigned short f2bf(float f) {
    unsigned int u = __float_as_uint(f);
    u += 0x7FFFu + ((u >> 16) & 1u);   // round-to-nearest-even
    return (unsigned short)(u >> 16);
}

__device__ __forceinline__ v8bf ld_bf8(const unsigned short* p) {
    u16x8 r = *(const u16x8*)p;
    return __builtin_bit_cast(v8bf, r);
}

// ---------------- Kernel A: build V = U[:, :64] (one column per block) + SIGNS row ----------------
__global__ __launch_bounds__(256) void build_VS(
        const float* __restrict__ rx0, const float* __restrict__ ry0,
        const float* __restrict__ ry1,
        unsigned short* __restrict__ Vre, unsigned short* __restrict__ Vim,
        unsigned short* __restrict__ S)
{
    __shared__ float sre[1024];
    __shared__ float sim[1024];
    const int c = blockIdx.x;     // feature column 0..63 == sign row h
    const int t = threadIdx.x;

    // hoist all params + trig (one latency hit, not 30 serialized ones)
    float cx[10], sx[10], cy0[10], sy0[10], cy1[10], sy1[10];
    #pragma unroll
    for (int j = 0; j < 10; ++j) {
        float hx = 0.5f * rx0[j], h0 = 0.5f * ry0[j], h1 = 0.5f * ry1[j];
        cx[j] = cosf(hx);  sx[j] = sinf(hx);
        cy0[j] = cosf(h0); sy0[j] = sinf(h0);
        cy1[j] = cosf(h1); sy1[j] = sinf(h1);
    }

    #pragma unroll
    for (int k = 0; k < 4; ++k) {
        int i = t + k * 256;
        sre[i] = (i == c) ? 1.0f : 0.0f;
        sim[i] = 0.0f;
    }
    __syncthreads();

    // Stage 1: G_j = RY(ry0_j) * RX(rx0_j) on qubit j (qubit j <-> bit 9-j)
    for (int j = 0; j < 10; ++j) {
        float g00r =  cy0[j] * cx[j], g00i =  sy0[j] * sx[j];
        float g01r = -sy0[j] * cx[j], g01i = -cy0[j] * sx[j];
        float g10r =  sy0[j] * cx[j], g10i = -cy0[j] * sx[j];
        float g11r =  cy0[j] * cx[j], g11i = -sy0[j] * sx[j];
        int p = 9 - j;
        int lowmask = (1 << p) - 1;
        #pragma unroll
        for (int it = 0; it < 2; ++it) {
            int idx = t + it * 256;
            int a = ((idx >> p) << (p + 1)) | (idx & lowmask);
            int b = a | (1 << p);
            float ar = sre[a], ai = sim[a], br = sre[b], bi = sim[b];
            sre[a] = g00r*ar - g00i*ai + g01r*br - g01i*bi;
            sim[a] = g00r*ai + g00i*ar + g01r*bi + g01i*br;
            sre[b] = g10r*ar - g10i*ai + g11r*br - g11i*bi;
            sim[b] = g10r*ai + g10i*ar + g11r*bi + g11i*br;
        }
        __syncthreads();
    }
    // Stage 2: CNOT ring j -> (j+1)%10
    for (int j = 0; j < 10; ++j) {
        int pc = 9 - j;
        int pt = 9 - ((j + 1) % 10);
        int p1 = pc < pt ? pc : pt;
        int p2 = pc < pt ? pt : pc;
        int x1 = ((t >> p1) << (p1 + 1)) | (t & ((1 << p1) - 1));
        int x2 = ((x1 >> p2) << (p2 + 1)) | (x1 & ((1 << p2) - 1));
        int i0 = x2 | (1 << pc);          // control=1, target=0
        int i1 = i0 | (1 << pt);
        float r0 = sre[i0], q0 = sim[i0];
        sre[i0] = sre[i1]; sim[i0] = sim[i1];
        sre[i1] = r0;      sim[i1] = q0;
        __syncthreads();
    }
    // Stage 3: RY(ry1_j)
    for (int j = 0; j < 10; ++j) {
        int p = 9 - j;
        int lowmask = (1 << p) - 1;
        #pragma unroll
        for (int it = 0; it < 2; ++it) {
            int idx = t + it * 256;
            int a = ((idx >> p) << (p + 1)) | (idx & lowmask);
            int b = a | (1 << p);
            float ar = sre[a], ai = sim[a], br = sre[b], bi = sim[b];
            sre[a] = cy1[j]*ar - sy1[j]*br;  sim[a] = cy1[j]*ai - sy1[j]*bi;
            sre[b] = sy1[j]*ar + cy1[j]*br;  sim[b] = sy1[j]*ai + cy1[j]*bi;
        }
        __syncthreads();
    }
    #pragma unroll
    for (int k = 0; k < 4; ++k) {
        int i = t + k * 256;
        Vre[i * 64 + c] = f2bf(sre[i]);
        Vim[i * 64 + c] = f2bf(sim[i]);
        // SIGNS row c: mask = c+1, S[c][i] = (-1)^popc(i & (c+1)) as bf16
        S[c * 1024 + i] = (__popc(i & (c + 1)) & 1) ? 0xBF80 : 0x3F80;
    }
}

// ---------------- Kernel B: fused  out = (|xn @ V^T|^2) @ S^T ----------------
// Independent waves: wave pair (w>>1) owns 16 tokens; w&1 selects K-half (chunks 0-7 / 8-15).
// V and S fragments loaded straight from global (L2-resident); no main-loop barriers.
__global__ __launch_bounds__(256, 2) void qsa_fused(
        const float* __restrict__ x,
        const unsigned short* __restrict__ Vre,
        const unsigned short* __restrict__ Vim,
        const unsigned short* __restrict__ S,
        float* __restrict__ out)
{
    __shared__ alignas(16) unsigned short pr[4][16][72];   // per-wave probs shuffle
    __shared__ float opart[2][16][66];                     // split-K partial handoff

    const int tid = threadIdx.x;
    const int w = tid >> 6;
    const int l = tid & 63;
    const int p = w >> 1;           // token-tile pair within block
    const int h2 = w & 1;           // K-half
    const int l15 = l & 15, lh = l >> 4;
    const int m0 = blockIdx.x * 32 + p * 16;   // this wave's 16 token rows

    // ---- load + normalize 16 tokens straight into A-fragments (no LDS) ----
    const float* xrow = x + (size_t)(m0 + l15) * 64;
    float4 v0 = *(const float4*)(xrow + lh * 8);
    float4 v1 = *(const float4*)(xrow + lh * 8 + 4);
    float4 v2 = *(const float4*)(xrow + 32 + lh * 8);
    float4 v3 = *(const float4*)(xrow + 32 + lh * 8 + 4);
    float ss = v0.x*v0.x + v0.y*v0.y + v0.z*v0.z + v0.w*v0.w
             + v1.x*v1.x + v1.y*v1.y + v1.z*v1.z + v1.w*v1.w
             + v2.x*v2.x + v2.y*v2.y + v2.z*v2.z + v2.w*v2.w
             + v3.x*v3.x + v3.y*v3.y + v3.z*v3.z + v3.w*v3.w;
    ss += __shfl_xor(ss, 16);
    ss += __shfl_xor(ss, 32);
    float rn = rsqrtf(ss);
    u16x8 ua0, ua1;
    ua0[0]=f2bf(v0.x*rn); ua0[1]=f2bf(v0.y*rn); ua0[2]=f2bf(v0.z*rn); ua0[3]=f2bf(v0.w*rn);
    ua0[4]=f2bf(v1.x*rn); ua0[5]=f2bf(v1.y*rn); ua0[6]=f2bf(v1.z*rn); ua0[7]=f2bf(v1.w*rn);
    ua1[0]=f2bf(v2.x*rn); ua1[1]=f2bf(v2.y*rn); ua1[2]=f2bf(v2.z*rn); ua1[3]=f2bf(v2.w*rn);
    ua1[4]=f2bf(v3.x*rn); ua1[5]=f2bf(v3.y*rn); ua1[6]=f2bf(v3.z*rn); ua1[7]=f2bf(v3.w*rn);
    v8bf a0 = __builtin_bit_cast(v8bf, ua0);
    v8bf a1 = __builtin_bit_cast(v8bf, ua1);

    v4f oacc[4];
    #pragma unroll
    for (int nb = 0; nb < 4; ++nb) oacc[nb] = (v4f){0.f,0.f,0.f,0.f};

    // per-lane fragment base pointers
    const unsigned short* vreb = Vre + (size_t)l15 * 64 + lh * 8;
    const unsigned short* vimb = Vim + (size_t)l15 * 64 + lh * 8;
    const unsigned short* sb   = S   + (size_t)l15 * 1024 + lh * 8;

    for (int cchunk = 0; cchunk < 8; ++cchunk) {
        const int s0 = (h2 * 8 + cchunk) * 64;

        // matmul1: psi = xn @ V^T  (complex, 2 real GEMMs), B-frags from global/L2
        v4f pre[4], pim[4];
        #pragma unroll
        for (int nb = 0; nb < 4; ++nb) {
            const size_t ro = (size_t)(s0 + nb * 16) * 64;
            v8bf br0 = ld_bf8(vreb + ro);
            v8bf br1 = ld_bf8(vreb + ro + 32);
            v8bf bi0 = ld_bf8(vimb + ro);
            v8bf bi1 = ld_bf8(vimb + ro + 32);
            v4f z = (v4f){0.f,0.f,0.f,0.f};
            v4f r = __builtin_amdgcn_mfma_f32_16x16x32_bf16(a0, br0, z, 0, 0, 0);
            r     = __builtin_amdgcn_mfma_f32_16x16x32_bf16(a1, br1, r, 0, 0, 0);
            v4f q = __builtin_amdgcn_mfma_f32_16x16x32_bf16(a0, bi0, z, 0, 0, 0);
            q     = __builtin_amdgcn_mfma_f32_16x16x32_bf16(a1, bi1, q, 0, 0, 0);
            pre[nb] = r; pim[nb] = q;
        }

        // probs = re^2+im^2 (fp32) -> bf16, wave-local LDS layout shuffle
        #pragma unroll
        for (int nb = 0; nb < 4; ++nb) {
            #pragma unroll
            for (int r = 0; r < 4; ++r) {
                float pv = pre[nb][r]*pre[nb][r] + pim[nb][r]*pim[nb][r];
                pr[w][lh*4 + r][nb*16 + l15] = f2bf(pv);
            }
        }
        v8bf pa0 = ld_bf8(&pr[w][l15][lh*8]);
        v8bf pa1 = ld_bf8(&pr[w][l15][32 + lh*8]);

        // matmul2: out += probs @ S^T, sign-frags from global/L2
        #pragma unroll
        for (int nb = 0; nb < 4; ++nb) {
            const size_t so = (size_t)(nb * 16) * 1024 + s0;
            v8bf sA = ld_bf8(sb + so);
            v8bf sB = ld_bf8(sb + so + 32);
            oacc[nb] = __builtin_amdgcn_mfma_f32_16x16x32_bf16(pa0, sA, oacc[nb], 0, 0, 0);
            oacc[nb] = __builtin_amdgcn_mfma_f32_16x16x32_bf16(pa1, sB, oacc[nb], 0, 0, 0);
        }
    }

    // ---- split-K combine: half 1 hands partials to half 0 via LDS ----
    if (h2 == 1) {
        #pragma unroll
        for (int nb = 0; nb < 4; ++nb)
            #pragma unroll
            for (int r = 0; r < 4; ++r)
                opart[p][lh*4 + r][nb*16 + l15] = oacc[nb][r];
    }
    __syncthreads();
    if (h2 == 0) {
        #pragma unroll
        for (int nb = 0; nb < 4; ++nb)
            #pragma unroll
            for (int r = 0; r < 4; ++r)
                out[(size_t)(m0 + lh*4 + r) * 64 + nb*16 + l15] =
                    oacc[nb][r] + opart[p][lh*4 + r][nb*16 + l15];
    }
}

extern "C" void kernel_launch(void* const* d_in, const int* in_sizes, int n_in,
                              void* d_out, int out_size, void* d_ws, size_t ws_size,
                              hipStream_t stream) {
    const float* x   = (const float*)d_in[0];
    const float* rx0 = (const float*)d_in[1];
    const float* ry0 = (const float*)d_in[2];
    const float* ry1 = (const float*)d_in[3];
    float* out = (float*)d_out;

    unsigned short* Vre = (unsigned short*)d_ws;            // 1024*64 bf16
    unsigned short* Vim = Vre + 1024 * 64;                  // 1024*64 bf16
    unsigned short* S   = Vim + 1024 * 64;                  // 64*1024 bf16 signs

    const int M = in_sizes[0] / 64;                         // tokens (B*T)

    build_VS<<<64, 256, 0, stream>>>(rx0, ry0, ry1, Vre, Vim, S);
    qsa_fused<<<M / 32, 256, 0, stream>>>(x, Vre, Vim, S, out);
}